// Round 4
// baseline (24941.373 us; speedup 1.0000x reference)
//
#include <hip/hip_runtime.h>

#define HD 768
#define G4 3072
#define T1 256
#define NS2 64
#define NL 3

#define LPB 96      // blocks per direction
#define LBLK 192    // total blocks (2 dirs)
#define LTHR 128    // threads per block

__device__ __forceinline__ float sigf(float x) { return 1.0f / (1.0f + expf(-x)); }

// ---------------------------------------------------------------------------
// Tiled f32 GEMM: C[m, jg] = sum_k A[m,k] * W[jg, k] (+ bias[jg])
// ---------------------------------------------------------------------------
__global__ __launch_bounds__(256) void gemm_f32(
    const float* __restrict__ A, int lda,
    const float* __restrict__ W, int ldw,
    const float* __restrict__ bias,
    float* __restrict__ C,
    int K, int n_per_chunk, long long chunk_stride)
{
    __shared__ __align__(16) float As[16 * 64];
    __shared__ __align__(16) float Ws[16 * 64];
    const int tid = threadIdx.x;
    const int tx = tid & 15, ty = tid >> 4;
    const int n0 = blockIdx.x * 64, m0 = blockIdx.y * 64;
    const int lr = tid >> 2, lc = tid & 3;

    float acc[4][4] = {{0.f}};
    const float* Ap = A + (size_t)(m0 + lr) * lda + lc * 4;
    const float* Wp = W + (size_t)(n0 + lr) * ldw + lc * 4;

    for (int k0 = 0; k0 < K; k0 += 16) {
        float4 av = *(const float4*)(Ap + k0);
        float4 wv = *(const float4*)(Wp + k0);
        __syncthreads();
        As[(lc * 4 + 0) * 64 + lr] = av.x;
        As[(lc * 4 + 1) * 64 + lr] = av.y;
        As[(lc * 4 + 2) * 64 + lr] = av.z;
        As[(lc * 4 + 3) * 64 + lr] = av.w;
        Ws[(lc * 4 + 0) * 64 + lr] = wv.x;
        Ws[(lc * 4 + 1) * 64 + lr] = wv.y;
        Ws[(lc * 4 + 2) * 64 + lr] = wv.z;
        Ws[(lc * 4 + 3) * 64 + lr] = wv.w;
        __syncthreads();
#pragma unroll
        for (int k = 0; k < 16; ++k) {
            float4 a = *(const float4*)&As[k * 64 + ty * 4];
            float4 b = *(const float4*)&Ws[k * 64 + tx * 4];
            float aa[4] = {a.x, a.y, a.z, a.w};
            float bb[4] = {b.x, b.y, b.z, b.w};
#pragma unroll
            for (int i = 0; i < 4; ++i)
#pragma unroll
                for (int j = 0; j < 4; ++j) acc[i][j] += aa[i] * bb[j];
        }
    }

    const int jg = n0 + tx * 4;
    const int chunk = jg / n_per_chunk;
    const int jo = jg - chunk * n_per_chunk;
    float4 bv = make_float4(0.f, 0.f, 0.f, 0.f);
    if (bias) bv = *(const float4*)&bias[jg];
    float* Cb = C + (size_t)chunk * chunk_stride + jo;
#pragma unroll
    for (int i = 0; i < 4; ++i) {
        const int m = m0 + ty * 4 + i;
        float4 o;
        o.x = acc[i][0] + bv.x;
        o.y = acc[i][1] + bv.y;
        o.z = acc[i][2] + bv.z;
        o.w = acc[i][3] + bv.w;
        *(float4*)&Cb[(size_t)m * n_per_chunk] = o;
    }
}

// ---------------------------------------------------------------------------
// Persistent BiLSTM layer. 192 blocks x 128 threads, plain launch (all blocks
// trivially co-resident on 256 CUs). h ping-pong in global, interleaved
// [k][b] layout, agent-scope atomics (sc1 -> LLC-coherent across XCDs),
// per-direction monotone counter barrier.
// LDS h staging uses a BIJECTIVE XOR swizzle: phys_slot(s) = s ^ ((s>>2)&7).
// (Round 3's additive skew s + ((s>>2)&7) was non-injective -> ~3% of h
// entries aliased -> absmax 4.4e-2. XOR swizzle is a bijection and makes the
// 8 k-slice lanesets hit 8 distinct bank-quads: conflict-free b128 reads.)
// ---------------------------------------------------------------------------
__global__ __launch_bounds__(LTHR, 1) void lstm_persist(
    const float* __restrict__ Whh,   // [2][3072][768]
    const float* __restrict__ G,     // [2][4][256][3072]
    float* __restrict__ hbuf,        // [2 parity][2 dir][768][4], zero-init
    float* __restrict__ Hout,        // [4][256][1536]
    unsigned int* __restrict__ cnt,  // [2], zero-init
    int last)
{
    __shared__ __align__(16) float hsw[3104];  // swizzled h, float4 slot per k
    __shared__ float gl[32][4];
    __shared__ float cs[32];

    const int tid = threadIdx.x;
    const int dir = blockIdx.x / LPB;
    const int wblk = blockIdx.x - dir * LPB;
    const int u0 = wblk * 8;

    const int ks = tid & 7;       // k-slice 0..7
    const int rg = tid >> 3;      // row-group 0..15 (2 rows each)
    const int jl0 = rg * 2, jl1 = jl0 + 1;
    const int j0 = (jl0 >> 3) * HD + u0 + (jl0 & 7);
    const int j1 = (jl1 >> 3) * HD + u0 + (jl1 & 7);

    // ---- preload weights into registers (2 rows x 24 float4) ----
    float4 w0r[24], w1r[24];
    {
        const float4* wp0 = (const float4*)(Whh + ((size_t)dir * G4 + j0) * HD);
        const float4* wp1 = (const float4*)(Whh + ((size_t)dir * G4 + j1) * HD);
#pragma unroll
        for (int it = 0; it < 24; ++it) {
            w0r[it] = wp0[it * 8 + ks];
            w1r[it] = wp1[it * 8 + ks];
        }
    }
    if (tid < 32) cs[tid] = 0.f;

    const size_t bstr = (size_t)T1 * G4;
    const float4* hs4 = (const float4*)hsw;

    for (int s = 0; s < T1; ++s) {
        const int t = dir ? (T1 - 1 - s) : s;

        // prefetch ih-gate preactivations (independent of h)
        float gin0[4], gin1[4];
        if (ks == 0) {
            const size_t gb = ((size_t)dir * 4 * T1 + t) * G4;
#pragma unroll
            for (int b = 0; b < 4; ++b) {
                gin0[b] = G[gb + b * bstr + j0];
                gin1[b] = G[gb + b * bstr + j1];
            }
        }

        // ---- stage h into LDS (coalesced global read, XOR-swizzled write) ----
        const float* hsrc = hbuf + ((size_t)(s & 1) * 2 + dir) * (4 * HD);
#pragma unroll
        for (int i = 0; i < 24; ++i) {
            const int idx = tid + i * LTHR;      // 0..3071 = k*4 + b
            const float v = __hip_atomic_load(hsrc + idx,
                                              __ATOMIC_RELAXED, __HIP_MEMORY_SCOPE_AGENT);
            const int k = idx >> 2, b = idx & 3;
            const int ph = k ^ ((k >> 2) & 7);   // bijective XOR swizzle
            hsw[(ph << 2) + b] = v;
        }
        __syncthreads();

        // ---- gate GEMV: 2 rows x 96 k x 4 batch per thread ----
        float a00 = 0.f, a01 = 0.f, a02 = 0.f, a03 = 0.f;
        float a10 = 0.f, a11 = 0.f, a12 = 0.f, a13 = 0.f;
#pragma unroll
        for (int it = 0; it < 24; ++it) {
            const int kq = it * 8 + ks;
            const int sb = kq * 4;               // logical slot base
            const float4 w0 = w0r[it], w1 = w1r[it];
            const float4 hA = hs4[(sb + 0) ^ ks];  // h[4kq+0], batches 0..3
            const float4 hB = hs4[(sb + 1) ^ ks];
            const float4 hC = hs4[(sb + 2) ^ ks];
            const float4 hD = hs4[(sb + 3) ^ ks];
            a00 += w0.x * hA.x + w0.y * hB.x + w0.z * hC.x + w0.w * hD.x;
            a01 += w0.x * hA.y + w0.y * hB.y + w0.z * hC.y + w0.w * hD.y;
            a02 += w0.x * hA.z + w0.y * hB.z + w0.z * hC.z + w0.w * hD.z;
            a03 += w0.x * hA.w + w0.y * hB.w + w0.z * hC.w + w0.w * hD.w;
            a10 += w1.x * hA.x + w1.y * hB.x + w1.z * hC.x + w1.w * hD.x;
            a11 += w1.x * hA.y + w1.y * hB.y + w1.z * hC.y + w1.w * hD.y;
            a12 += w1.x * hA.z + w1.y * hB.z + w1.z * hC.z + w1.w * hD.z;
            a13 += w1.x * hA.w + w1.y * hB.w + w1.z * hC.w + w1.w * hD.w;
        }
#pragma unroll
        for (int off = 1; off < 8; off <<= 1) {
            a00 += __shfl_xor(a00, off); a01 += __shfl_xor(a01, off);
            a02 += __shfl_xor(a02, off); a03 += __shfl_xor(a03, off);
            a10 += __shfl_xor(a10, off); a11 += __shfl_xor(a11, off);
            a12 += __shfl_xor(a12, off); a13 += __shfl_xor(a13, off);
        }
        if (ks == 0) {
            gl[jl0][0] = a00 + gin0[0]; gl[jl0][1] = a01 + gin0[1];
            gl[jl0][2] = a02 + gin0[2]; gl[jl0][3] = a03 + gin0[3];
            gl[jl1][0] = a10 + gin1[0]; gl[jl1][1] = a11 + gin1[1];
            gl[jl1][2] = a12 + gin1[2]; gl[jl1][3] = a13 + gin1[3];
        }
        __syncthreads();

        // ---- cell update: 32 threads = 8 units x 4 batch ----
        if (tid < 32) {
            const int ui = tid >> 2, b = tid & 3;
            const int u = u0 + ui;
            const float gi = gl[0 * 8 + ui][b];
            const float gf = gl[1 * 8 + ui][b];
            const float gg = gl[2 * 8 + ui][b];
            const float go = gl[3 * 8 + ui][b];
            const float c = sigf(gf) * cs[tid] + sigf(gi) * tanhf(gg);
            const float h = sigf(go) * tanhf(c);
            cs[tid] = c;
            float* hdst = hbuf + ((size_t)((s + 1) & 1) * 2 + dir) * (4 * HD);
            __hip_atomic_store(hdst + (u << 2) + b, h,
                               __ATOMIC_RELAXED, __HIP_MEMORY_SCOPE_AGENT);
            Hout[((size_t)b * T1 + t) * (2 * HD) + dir * HD + u] = last ? tanhf(h) : h;
        }
        __syncthreads();

        // ---- per-direction barrier (monotone counter, device scope) ----
        if (tid == 0) {
            __threadfence();
            __hip_atomic_fetch_add(&cnt[dir], 1u,
                                   __ATOMIC_RELEASE, __HIP_MEMORY_SCOPE_AGENT);
            const unsigned int target = (unsigned int)(s + 1) * LPB;
            while (__hip_atomic_load(&cnt[dir], __ATOMIC_ACQUIRE,
                                     __HIP_MEMORY_SCOPE_AGENT) < target) {
                __builtin_amdgcn_s_sleep(1);
            }
        }
        __syncthreads();
    }
}

// ---------------------------------------------------------------------------
// Attention: per (b,q) block.
// ---------------------------------------------------------------------------
__global__ __launch_bounds__(256) void attn_kernel(
    const float* __restrict__ hq,
    const float* __restrict__ hk,
    const float* __restrict__ w2p,
    const float* __restrict__ b2p,
    const float* __restrict__ am,
    const float* __restrict__ sm,
    const float* __restrict__ H3,
    float* __restrict__ sf)
{
    __shared__ float hql[HD];
    __shared__ float w2[HD];
    __shared__ float Ash[T1];
    __shared__ float red[1];
    const int tid = threadIdx.x;
    const int bq = blockIdx.x;
    const int b = bq >> 6;

    for (int e = tid; e < HD; e += 256) {
        hql[e] = hq[(size_t)bq * HD + e];
        w2[e] = w2p[e];
    }
    __syncthreads();

    const int lane = tid & 63, wid = tid >> 6;
    const float amv = am[bq];
    const float b2 = b2p[0];
    for (int k = wid; k < T1; k += 4) {
        const float* hkp = hk + ((size_t)b * T1 + k) * HD;
        float s = 0.f;
#pragma unroll
        for (int i = 0; i < 12; ++i) {
            const int e = i * 64 + lane;
            float v = hql[e] + hkp[e];
            v = v > 0.f ? v : 0.f;
            s += v * w2[e];
        }
#pragma unroll
        for (int off = 32; off; off >>= 1) s += __shfl_xor(s, off);
        if (lane == 0) {
            const float m = amv * sm[b * T1 + k];
            Ash[k] = (m == 0.f) ? 0.f : expf(s + b2);
        }
    }
    __syncthreads();

    if (tid < 64) {
        float p = Ash[tid] + Ash[tid + 64] + Ash[tid + 128] + Ash[tid + 192];
#pragma unroll
        for (int off = 32; off; off >>= 1) p += __shfl_xor(p, off);
        if (tid == 0) red[0] = fmaxf(p, 2e-15f);
    }
    __syncthreads();
    const float inv = 1.f / red[0];

    for (int d = tid; d < 2 * HD; d += 256) {
        const float* hp = H3 + (size_t)b * T1 * 2 * HD + d;
        float acc = 0.f;
        for (int k = 0; k < T1; ++k) acc += Ash[k] * hp[(size_t)k * 2 * HD];
        sf[(size_t)bq * 2 * HD + d] = acc * inv;
    }
}

__global__ __launch_bounds__(256) void val_kernel(
    const float* __restrict__ sf, const float* __restrict__ am,
    const float* __restrict__ vw, const float* __restrict__ vb,
    float* __restrict__ val)
{
    __shared__ float red[4];
    const int b = blockIdx.x, tid = threadIdx.x;
    float num = 0.f;
    for (int q = 0; q < NS2; ++q) num += am[b * NS2 + q];
    float acc = 0.f;
    for (int d = tid; d < 2 * HD; d += 256) {
        float s = 0.f;
        for (int q = 0; q < NS2; ++q) s += sf[((size_t)(b * NS2 + q)) * 2 * HD + d];
        acc += (s / num) * vw[d];
    }
#pragma unroll
    for (int off = 32; off; off >>= 1) acc += __shfl_xor(acc, off);
    if ((tid & 63) == 0) red[tid >> 6] = acc;
    __syncthreads();
    if (tid == 0) val[b] = red[0] + red[1] + red[2] + red[3] + vb[0];
}

__global__ __launch_bounds__(256) void final_kernel(
    const float* __restrict__ Tb,   // [3][256][768]
    const float* __restrict__ act,  // [4][64][768]
    const float* __restrict__ bias, // [3]
    const float* __restrict__ val,  // [4]
    float* __restrict__ out)        // [256][3]
{
    __shared__ float adv[192];
    __shared__ float red[4];
    const int b = blockIdx.x, tid = threadIdx.x;
    const int lane = tid & 63, wid = tid >> 6;

    for (int idx = wid; idx < 192; idx += 4) {
        const int q = idx / 3, l = idx - q * 3;
        const float* tp = Tb + (size_t)l * T1 * HD + (size_t)(b * NS2 + q) * HD;
        const float* ap = act + (size_t)(b * NS2 + q) * HD;
        float s = 0.f;
#pragma unroll
        for (int i = 0; i < 12; ++i) {
            const int h = i * 64 + lane;
            s += tp[h] * ap[h];
        }
#pragma unroll
        for (int off = 32; off; off >>= 1) s += __shfl_xor(s, off);
        if (lane == 0) adv[idx] = s + bias[l];
    }
    __syncthreads();
    float part = (tid < 192) ? adv[tid] : 0.f;
#pragma unroll
    for (int off = 32; off; off >>= 1) part += __shfl_xor(part, off);
    if (lane == 0) red[wid] = part;
    __syncthreads();
    const float mean = (red[0] + red[1] + red[2] + red[3]) * (1.f / 192.f);
    const float vv = val[b];
    for (int idx = tid; idx < 192; idx += 256) {
        const int q = idx / 3, l = idx - q * 3;
        out[(size_t)(b * NS2 + q) * NL + l] = vv + adv[idx] - mean;
    }
}

// ---------------------------------------------------------------------------
extern "C" void kernel_launch(void* const* d_in, const int* in_sizes, int n_in,
                              void* d_out, int out_size, void* d_ws, size_t ws_size,
                              hipStream_t stream)
{
    const float* states = (const float*)d_in[0];
    const float* state_mask = (const float*)d_in[1];
    const float* actions = (const float*)d_in[2];
    const float* actions_mask = (const float*)d_in[3];
    const float* Wih0 = (const float*)d_in[4];
    const float* Whh0 = (const float*)d_in[5];
    const float* b0 = (const float*)d_in[6];
    const float* Wih12 = (const float*)d_in[7];
    const float* Whh12 = (const float*)d_in[8];
    const float* b12 = (const float*)d_in[9];
    const float* aW1 = (const float*)d_in[10];
    const float* ab1 = (const float*)d_in[11];
    const float* aW2 = (const float*)d_in[12];
    const float* ab2 = (const float*)d_in[13];
    const float* vW = (const float*)d_in[14];
    const float* vb = (const float*)d_in[15];
    const float* wgt = (const float*)d_in[16];
    const float* bias = (const float*)d_in[17];
    float* out = (float*)d_out;

    float* ws = (float*)d_ws;
    float* G = ws;                        // 6291456 floats
    float* B1 = G + 6291456;              // 1572864
    float* B2 = B1 + 1572864;             // 1572864
    float* hbuf = B2 + 1572864;           // 12288 floats
    unsigned int* cnt = (unsigned int*)(hbuf + 12288);  // 2 uints
    // attention-phase aliases over G:
    float* hq = G;                        // 196608
    float* hkb = G + 196608;              // 786432
    float* sf = G + 983040;               // 393216
    float* Tb = G + 1376256;              // 589824
    float* val = G + 1966080;             // 4

    const dim3 blk(256);
    const long long gstride = (long long)4 * T1 * G4;

    const float* WhhL[3] = {Whh0, Whh12, Whh12 + (size_t)2 * G4 * HD};
    float* HoutL[3] = {B1, B2, B1};

    for (int l = 0; l < 3; ++l) {
        hipMemsetAsync(hbuf, 0, 12288 * sizeof(float), stream);
        hipMemsetAsync(cnt, 0, 2 * sizeof(unsigned int), stream);
        if (l == 0) {
            gemm_f32<<<dim3(6144 / 64, 1024 / 64), blk, 0, stream>>>(
                states, HD, Wih0, HD, b0, G, HD, G4, gstride);
        } else {
            const float* src = (l == 1) ? B1 : B2;
            const float* Wih = Wih12 + (size_t)(l - 1) * 6144 * 1536;
            const float* bb = b12 + (size_t)(l - 1) * 6144;
            gemm_f32<<<dim3(6144 / 64, 1024 / 64), blk, 0, stream>>>(
                src, 2 * HD, Wih, 2 * HD, bb, G, 2 * HD, G4, gstride);
        }
        lstm_persist<<<dim3(LBLK), dim3(LTHR), 0, stream>>>(
            WhhL[l], G, hbuf, HoutL[l], cnt, (l == 2) ? 1 : 0);
    }

    // ---------------- attention ----------------
    gemm_f32<<<dim3(768 / 64, 256 / 64), blk, 0, stream>>>(
        actions, HD, aW1, 2304, ab1, hq, HD, HD, 0);
    gemm_f32<<<dim3(768 / 64, 1024 / 64), blk, 0, stream>>>(
        B1, 2 * HD, aW1 + 768, 2304, nullptr, hkb, 2 * HD, HD, 0);
    attn_kernel<<<dim3(256), blk, 0, stream>>>(hq, hkb, aW2, ab2, actions_mask,
                                               state_mask, B1, sf);
    val_kernel<<<dim3(4), blk, 0, stream>>>(sf, actions_mask, vW, vb, val);
    for (int l = 0; l < NL; ++l) {
        gemm_f32<<<dim3(768 / 64, 256 / 64), blk, 0, stream>>>(
            sf, 2 * HD, wgt + (size_t)l * HD * 2 * HD, 2 * HD, nullptr,
            Tb + (size_t)l * T1 * HD, 2 * HD, HD, 0);
    }
    final_kernel<<<dim3(4), blk, 0, stream>>>(Tb, actions, bias, val, out);
}

// Round 5
// 18169.620 us; speedup vs baseline: 1.3727x; 1.3727x over previous
//
#include <hip/hip_runtime.h>

#define HD 768
#define G4 3072
#define T1 256
#define NS2 64
#define NL 3

#define LPB 96      // blocks per direction
#define LBLK 192    // total blocks (2 dirs)
#define LTHR 128    // threads per block
#define CNTPAD 64   // uints between the two direction counters (256 B)

__device__ __forceinline__ float sigf(float x) { return 1.0f / (1.0f + expf(-x)); }

// ---------------------------------------------------------------------------
// Tiled f32 GEMM: C[m, jg] = sum_k A[m,k] * W[jg, k] (+ bias[jg])
// ---------------------------------------------------------------------------
__global__ __launch_bounds__(256) void gemm_f32(
    const float* __restrict__ A, int lda,
    const float* __restrict__ W, int ldw,
    const float* __restrict__ bias,
    float* __restrict__ C,
    int K, int n_per_chunk, long long chunk_stride)
{
    __shared__ __align__(16) float As[16 * 64];
    __shared__ __align__(16) float Ws[16 * 64];
    const int tid = threadIdx.x;
    const int tx = tid & 15, ty = tid >> 4;
    const int n0 = blockIdx.x * 64, m0 = blockIdx.y * 64;
    const int lr = tid >> 2, lc = tid & 3;

    float acc[4][4] = {{0.f}};
    const float* Ap = A + (size_t)(m0 + lr) * lda + lc * 4;
    const float* Wp = W + (size_t)(n0 + lr) * ldw + lc * 4;

    for (int k0 = 0; k0 < K; k0 += 16) {
        float4 av = *(const float4*)(Ap + k0);
        float4 wv = *(const float4*)(Wp + k0);
        __syncthreads();
        As[(lc * 4 + 0) * 64 + lr] = av.x;
        As[(lc * 4 + 1) * 64 + lr] = av.y;
        As[(lc * 4 + 2) * 64 + lr] = av.z;
        As[(lc * 4 + 3) * 64 + lr] = av.w;
        Ws[(lc * 4 + 0) * 64 + lr] = wv.x;
        Ws[(lc * 4 + 1) * 64 + lr] = wv.y;
        Ws[(lc * 4 + 2) * 64 + lr] = wv.z;
        Ws[(lc * 4 + 3) * 64 + lr] = wv.w;
        __syncthreads();
#pragma unroll
        for (int k = 0; k < 16; ++k) {
            float4 a = *(const float4*)&As[k * 64 + ty * 4];
            float4 b = *(const float4*)&Ws[k * 64 + tx * 4];
            float aa[4] = {a.x, a.y, a.z, a.w};
            float bb[4] = {b.x, b.y, b.z, b.w};
#pragma unroll
            for (int i = 0; i < 4; ++i)
#pragma unroll
                for (int j = 0; j < 4; ++j) acc[i][j] += aa[i] * bb[j];
        }
    }

    const int jg = n0 + tx * 4;
    const int chunk = jg / n_per_chunk;
    const int jo = jg - chunk * n_per_chunk;
    float4 bv = make_float4(0.f, 0.f, 0.f, 0.f);
    if (bias) bv = *(const float4*)&bias[jg];
    float* Cb = C + (size_t)chunk * chunk_stride + jo;
#pragma unroll
    for (int i = 0; i < 4; ++i) {
        const int m = m0 + ty * 4 + i;
        float4 o;
        o.x = acc[i][0] + bv.x;
        o.y = acc[i][1] + bv.y;
        o.z = acc[i][2] + bv.z;
        o.w = acc[i][3] + bv.w;
        *(float4*)&Cb[(size_t)m * n_per_chunk] = o;
    }
}

// ---------------------------------------------------------------------------
// Persistent BiLSTM layer. 192 blocks x 128 threads, plain launch (all blocks
// trivially co-resident on 256 CUs).
// SYNC DESIGN (round 5): all cross-block data (h ping-pong, counters) moves
// through agent-scope RELAXED atomics -> sc1 ops served at the coherent LLC,
// bypassing the non-coherent per-XCD L2. No acquire/release anywhere: acquire
// polls were emitting an L2 buffer_inv PER POLL ITERATION (round 4: 31 us/step,
// VALUBusy 2%). Ordering "h stores visible before counter add" is provided by
// __syncthreads(), whose s_barrier is preceded by s_waitcnt vmcnt(0) = LLC
// write-acks drained. Counters padded to separate 256B lines per direction.
// ---------------------------------------------------------------------------
__global__ __launch_bounds__(LTHR, 1) void lstm_persist(
    const float* __restrict__ Whh,   // [2][3072][768]
    const float* __restrict__ G,     // [2][4][256][3072]
    float* __restrict__ hbuf,        // [2 parity][2 dir][768][4], zero-init
    float* __restrict__ Hout,        // [4][256][1536]
    unsigned int* __restrict__ cnt,  // [2*CNTPAD], zero-init
    int last)
{
    __shared__ __align__(16) float hsw[3104];  // swizzled h, float4 slot per k
    __shared__ float gl[32][4];
    __shared__ float cs[32];

    const int tid = threadIdx.x;
    const int dir = blockIdx.x / LPB;
    const int wblk = blockIdx.x - dir * LPB;
    const int u0 = wblk * 8;

    const int ks = tid & 7;       // k-slice 0..7
    const int rg = tid >> 3;      // row-group 0..15 (2 rows each)
    const int jl0 = rg * 2, jl1 = jl0 + 1;
    const int j0 = (jl0 >> 3) * HD + u0 + (jl0 & 7);
    const int j1 = (jl1 >> 3) * HD + u0 + (jl1 & 7);

    // ---- preload weights into registers (2 rows x 24 float4) ----
    float4 w0r[24], w1r[24];
    {
        const float4* wp0 = (const float4*)(Whh + ((size_t)dir * G4 + j0) * HD);
        const float4* wp1 = (const float4*)(Whh + ((size_t)dir * G4 + j1) * HD);
#pragma unroll
        for (int it = 0; it < 24; ++it) {
            w0r[it] = wp0[it * 8 + ks];
            w1r[it] = wp1[it * 8 + ks];
        }
    }
    if (tid < 32) cs[tid] = 0.f;

    unsigned int* mycnt = cnt + dir * CNTPAD;
    const size_t bstr = (size_t)T1 * G4;
    const float4* hs4 = (const float4*)hsw;

    for (int s = 0; s < T1; ++s) {
        const int t = dir ? (T1 - 1 - s) : s;

        // prefetch ih-gate preactivations (independent of h)
        float gin0[4], gin1[4];
        if (ks == 0) {
            const size_t gb = ((size_t)dir * 4 * T1 + t) * G4;
#pragma unroll
            for (int b = 0; b < 4; ++b) {
                gin0[b] = G[gb + b * bstr + j0];
                gin1[b] = G[gb + b * bstr + j1];
            }
        }

        // ---- stage h into LDS (coalesced LLC read, XOR-swizzled write) ----
        const float* hsrc = hbuf + ((size_t)(s & 1) * 2 + dir) * (4 * HD);
#pragma unroll
        for (int i = 0; i < 24; ++i) {
            const int idx = tid + i * LTHR;      // 0..3071 = k*4 + b
            const float v = __hip_atomic_load(hsrc + idx,
                                              __ATOMIC_RELAXED, __HIP_MEMORY_SCOPE_AGENT);
            const int k = idx >> 2, b = idx & 3;
            const int ph = k ^ ((k >> 2) & 7);   // bijective XOR swizzle
            hsw[(ph << 2) + b] = v;
        }
        __syncthreads();

        // ---- gate GEMV: 2 rows x 96 k x 4 batch per thread ----
        float a00 = 0.f, a01 = 0.f, a02 = 0.f, a03 = 0.f;
        float a10 = 0.f, a11 = 0.f, a12 = 0.f, a13 = 0.f;
#pragma unroll
        for (int it = 0; it < 24; ++it) {
            const int kq = it * 8 + ks;
            const int sb = kq * 4;               // logical slot base
            const float4 w0 = w0r[it], w1 = w1r[it];
            const float4 hA = hs4[(sb + 0) ^ ks];  // h[4kq+0], batches 0..3
            const float4 hB = hs4[(sb + 1) ^ ks];
            const float4 hC = hs4[(sb + 2) ^ ks];
            const float4 hD = hs4[(sb + 3) ^ ks];
            a00 += w0.x * hA.x + w0.y * hB.x + w0.z * hC.x + w0.w * hD.x;
            a01 += w0.x * hA.y + w0.y * hB.y + w0.z * hC.y + w0.w * hD.y;
            a02 += w0.x * hA.z + w0.y * hB.z + w0.z * hC.z + w0.w * hD.z;
            a03 += w0.x * hA.w + w0.y * hB.w + w0.z * hC.w + w0.w * hD.w;
            a10 += w1.x * hA.x + w1.y * hB.x + w1.z * hC.x + w1.w * hD.x;
            a11 += w1.x * hA.y + w1.y * hB.y + w1.z * hC.y + w1.w * hD.y;
            a12 += w1.x * hA.z + w1.y * hB.z + w1.z * hC.z + w1.w * hD.z;
            a13 += w1.x * hA.w + w1.y * hB.w + w1.z * hC.w + w1.w * hD.w;
        }
#pragma unroll
        for (int off = 1; off < 8; off <<= 1) {
            a00 += __shfl_xor(a00, off); a01 += __shfl_xor(a01, off);
            a02 += __shfl_xor(a02, off); a03 += __shfl_xor(a03, off);
            a10 += __shfl_xor(a10, off); a11 += __shfl_xor(a11, off);
            a12 += __shfl_xor(a12, off); a13 += __shfl_xor(a13, off);
        }
        if (ks == 0) {
            gl[jl0][0] = a00 + gin0[0]; gl[jl0][1] = a01 + gin0[1];
            gl[jl0][2] = a02 + gin0[2]; gl[jl0][3] = a03 + gin0[3];
            gl[jl1][0] = a10 + gin1[0]; gl[jl1][1] = a11 + gin1[1];
            gl[jl1][2] = a12 + gin1[2]; gl[jl1][3] = a13 + gin1[3];
        }
        __syncthreads();

        // ---- cell update: 32 threads = 8 units x 4 batch ----
        if (tid < 32) {
            const int ui = tid >> 2, b = tid & 3;
            const int u = u0 + ui;
            const float gi = gl[0 * 8 + ui][b];
            const float gf = gl[1 * 8 + ui][b];
            const float gg = gl[2 * 8 + ui][b];
            const float go = gl[3 * 8 + ui][b];
            const float c = sigf(gf) * cs[tid] + sigf(gi) * tanhf(gg);
            const float h = sigf(go) * tanhf(c);
            cs[tid] = c;
            float* hdst = hbuf + ((size_t)((s + 1) & 1) * 2 + dir) * (4 * HD);
            __hip_atomic_store(hdst + (u << 2) + b, h,
                               __ATOMIC_RELAXED, __HIP_MEMORY_SCOPE_AGENT);
            Hout[((size_t)b * T1 + t) * (2 * HD) + dir * HD + u] = last ? tanhf(h) : h;
        }
        // drains vmcnt(0): h store write-acks from LLC complete before barrier
        __syncthreads();

        // ---- per-direction barrier: RELAXED monotone counter, no cache ops ----
        if (tid == 0) {
            __hip_atomic_fetch_add(mycnt, 1u,
                                   __ATOMIC_RELAXED, __HIP_MEMORY_SCOPE_AGENT);
            const unsigned int target = (unsigned int)(s + 1) * LPB;
            while (__hip_atomic_load(mycnt, __ATOMIC_RELAXED,
                                     __HIP_MEMORY_SCOPE_AGENT) < target) {
                __builtin_amdgcn_s_sleep(2);
            }
        }
        __syncthreads();
    }
}

// ---------------------------------------------------------------------------
// Attention: per (b,q) block.
// ---------------------------------------------------------------------------
__global__ __launch_bounds__(256) void attn_kernel(
    const float* __restrict__ hq,
    const float* __restrict__ hk,
    const float* __restrict__ w2p,
    const float* __restrict__ b2p,
    const float* __restrict__ am,
    const float* __restrict__ sm,
    const float* __restrict__ H3,
    float* __restrict__ sf)
{
    __shared__ float hql[HD];
    __shared__ float w2[HD];
    __shared__ float Ash[T1];
    __shared__ float red[1];
    const int tid = threadIdx.x;
    const int bq = blockIdx.x;
    const int b = bq >> 6;

    for (int e = tid; e < HD; e += 256) {
        hql[e] = hq[(size_t)bq * HD + e];
        w2[e] = w2p[e];
    }
    __syncthreads();

    const int lane = tid & 63, wid = tid >> 6;
    const float amv = am[bq];
    const float b2 = b2p[0];
    for (int k = wid; k < T1; k += 4) {
        const float* hkp = hk + ((size_t)b * T1 + k) * HD;
        float s = 0.f;
#pragma unroll
        for (int i = 0; i < 12; ++i) {
            const int e = i * 64 + lane;
            float v = hql[e] + hkp[e];
            v = v > 0.f ? v : 0.f;
            s += v * w2[e];
        }
#pragma unroll
        for (int off = 32; off; off >>= 1) s += __shfl_xor(s, off);
        if (lane == 0) {
            const float m = amv * sm[b * T1 + k];
            Ash[k] = (m == 0.f) ? 0.f : expf(s + b2);
        }
    }
    __syncthreads();

    if (tid < 64) {
        float p = Ash[tid] + Ash[tid + 64] + Ash[tid + 128] + Ash[tid + 192];
#pragma unroll
        for (int off = 32; off; off >>= 1) p += __shfl_xor(p, off);
        if (tid == 0) red[0] = fmaxf(p, 2e-15f);
    }
    __syncthreads();
    const float inv = 1.f / red[0];

    for (int d = tid; d < 2 * HD; d += 256) {
        const float* hp = H3 + (size_t)b * T1 * 2 * HD + d;
        float acc = 0.f;
        for (int k = 0; k < T1; ++k) acc += Ash[k] * hp[(size_t)k * 2 * HD];
        sf[(size_t)bq * 2 * HD + d] = acc * inv;
    }
}

__global__ __launch_bounds__(256) void val_kernel(
    const float* __restrict__ sf, const float* __restrict__ am,
    const float* __restrict__ vw, const float* __restrict__ vb,
    float* __restrict__ val)
{
    __shared__ float red[4];
    const int b = blockIdx.x, tid = threadIdx.x;
    float num = 0.f;
    for (int q = 0; q < NS2; ++q) num += am[b * NS2 + q];
    float acc = 0.f;
    for (int d = tid; d < 2 * HD; d += 256) {
        float s = 0.f;
        for (int q = 0; q < NS2; ++q) s += sf[((size_t)(b * NS2 + q)) * 2 * HD + d];
        acc += (s / num) * vw[d];
    }
#pragma unroll
    for (int off = 32; off; off >>= 1) acc += __shfl_xor(acc, off);
    if ((tid & 63) == 0) red[tid >> 6] = acc;
    __syncthreads();
    if (tid == 0) val[b] = red[0] + red[1] + red[2] + red[3] + vb[0];
}

__global__ __launch_bounds__(256) void final_kernel(
    const float* __restrict__ Tb,   // [3][256][768]
    const float* __restrict__ act,  // [4][64][768]
    const float* __restrict__ bias, // [3]
    const float* __restrict__ val,  // [4]
    float* __restrict__ out)        // [256][3]
{
    __shared__ float adv[192];
    __shared__ float red[4];
    const int b = blockIdx.x, tid = threadIdx.x;
    const int lane = tid & 63, wid = tid >> 6;

    for (int idx = wid; idx < 192; idx += 4) {
        const int q = idx / 3, l = idx - q * 3;
        const float* tp = Tb + (size_t)l * T1 * HD + (size_t)(b * NS2 + q) * HD;
        const float* ap = act + (size_t)(b * NS2 + q) * HD;
        float s = 0.f;
#pragma unroll
        for (int i = 0; i < 12; ++i) {
            const int h = i * 64 + lane;
            s += tp[h] * ap[h];
        }
#pragma unroll
        for (int off = 32; off; off >>= 1) s += __shfl_xor(s, off);
        if (lane == 0) adv[idx] = s + bias[l];
    }
    __syncthreads();
    float part = (tid < 192) ? adv[tid] : 0.f;
#pragma unroll
    for (int off = 32; off; off >>= 1) part += __shfl_xor(part, off);
    if (lane == 0) red[wid] = part;
    __syncthreads();
    const float mean = (red[0] + red[1] + red[2] + red[3]) * (1.f / 192.f);
    const float vv = val[b];
    for (int idx = tid; idx < 192; idx += 256) {
        const int q = idx / 3, l = idx - q * 3;
        out[(size_t)(b * NS2 + q) * NL + l] = vv + adv[idx] - mean;
    }
}

// ---------------------------------------------------------------------------
extern "C" void kernel_launch(void* const* d_in, const int* in_sizes, int n_in,
                              void* d_out, int out_size, void* d_ws, size_t ws_size,
                              hipStream_t stream)
{
    const float* states = (const float*)d_in[0];
    const float* state_mask = (const float*)d_in[1];
    const float* actions = (const float*)d_in[2];
    const float* actions_mask = (const float*)d_in[3];
    const float* Wih0 = (const float*)d_in[4];
    const float* Whh0 = (const float*)d_in[5];
    const float* b0 = (const float*)d_in[6];
    const float* Wih12 = (const float*)d_in[7];
    const float* Whh12 = (const float*)d_in[8];
    const float* b12 = (const float*)d_in[9];
    const float* aW1 = (const float*)d_in[10];
    const float* ab1 = (const float*)d_in[11];
    const float* aW2 = (const float*)d_in[12];
    const float* ab2 = (const float*)d_in[13];
    const float* vW = (const float*)d_in[14];
    const float* vb = (const float*)d_in[15];
    const float* wgt = (const float*)d_in[16];
    const float* bias = (const float*)d_in[17];
    float* out = (float*)d_out;

    float* ws = (float*)d_ws;
    float* G = ws;                        // 6291456 floats
    float* B1 = G + 6291456;              // 1572864
    float* B2 = B1 + 1572864;             // 1572864
    float* hbuf = B2 + 1572864;           // 12288 floats
    unsigned int* cnt = (unsigned int*)(hbuf + 12288);  // 2*CNTPAD uints
    // attention-phase aliases over G:
    float* hq = G;                        // 196608
    float* hkb = G + 196608;              // 786432
    float* sf = G + 983040;               // 393216
    float* Tb = G + 1376256;              // 589824
    float* val = G + 1966080;             // 4

    const dim3 blk(256);
    const long long gstride = (long long)4 * T1 * G4;

    const float* WhhL[3] = {Whh0, Whh12, Whh12 + (size_t)2 * G4 * HD};
    float* HoutL[3] = {B1, B2, B1};

    for (int l = 0; l < 3; ++l) {
        hipMemsetAsync(hbuf, 0, 12288 * sizeof(float), stream);
        hipMemsetAsync(cnt, 0, 2 * CNTPAD * sizeof(unsigned int), stream);
        if (l == 0) {
            gemm_f32<<<dim3(6144 / 64, 1024 / 64), blk, 0, stream>>>(
                states, HD, Wih0, HD, b0, G, HD, G4, gstride);
        } else {
            const float* src = (l == 1) ? B1 : B2;
            const float* Wih = Wih12 + (size_t)(l - 1) * 6144 * 1536;
            const float* bb = b12 + (size_t)(l - 1) * 6144;
            gemm_f32<<<dim3(6144 / 64, 1024 / 64), blk, 0, stream>>>(
                src, 2 * HD, Wih, 2 * HD, bb, G, 2 * HD, G4, gstride);
        }
        lstm_persist<<<dim3(LBLK), dim3(LTHR), 0, stream>>>(
            WhhL[l], G, hbuf, HoutL[l], cnt, (l == 2) ? 1 : 0);
    }

    // ---------------- attention ----------------
    gemm_f32<<<dim3(768 / 64, 256 / 64), blk, 0, stream>>>(
        actions, HD, aW1, 2304, ab1, hq, HD, HD, 0);
    gemm_f32<<<dim3(768 / 64, 1024 / 64), blk, 0, stream>>>(
        B1, 2 * HD, aW1 + 768, 2304, nullptr, hkb, 2 * HD, HD, 0);
    attn_kernel<<<dim3(256), blk, 0, stream>>>(hq, hkb, aW2, ab2, actions_mask,
                                               state_mask, B1, sf);
    val_kernel<<<dim3(4), blk, 0, stream>>>(sf, actions_mask, vW, vb, val);
    for (int l = 0; l < NL; ++l) {
        gemm_f32<<<dim3(768 / 64, 256 / 64), blk, 0, stream>>>(
            sf, 2 * HD, wgt + (size_t)l * HD * 2 * HD, 2 * HD, nullptr,
            Tb + (size_t)l * T1 * HD, 2 * HD, HD, 0);
    }
    final_kernel<<<dim3(4), blk, 0, stream>>>(Tb, actions, bias, val, out);
}

// Round 6
// 14061.090 us; speedup vs baseline: 1.7738x; 1.2922x over previous
//
#include <hip/hip_runtime.h>

#define HD 768
#define G4 3072
#define T1 256
#define NS2 64
#define NL 3

#define LPB 48      // blocks per direction
#define LBLK 96     // total blocks (2 dirs)
#define LTHR 256    // threads per block
#define UPB 16      // hidden units per block (64 gate rows)
#define SPAD 64     // uints per stamp/flag line (256 B)

__device__ __forceinline__ float sigf(float x) { return 1.0f / (1.0f + expf(-x)); }

// ---------------------------------------------------------------------------
// Tiled f32 GEMM: C[m, jg] = sum_k A[m,k] * W[jg, k] (+ bias[jg])
// ---------------------------------------------------------------------------
__global__ __launch_bounds__(256) void gemm_f32(
    const float* __restrict__ A, int lda,
    const float* __restrict__ W, int ldw,
    const float* __restrict__ bias,
    float* __restrict__ C,
    int K, int n_per_chunk, long long chunk_stride)
{
    __shared__ __align__(16) float As[16 * 64];
    __shared__ __align__(16) float Ws[16 * 64];
    const int tid = threadIdx.x;
    const int tx = tid & 15, ty = tid >> 4;
    const int n0 = blockIdx.x * 64, m0 = blockIdx.y * 64;
    const int lr = tid >> 2, lc = tid & 3;

    float acc[4][4] = {{0.f}};
    const float* Ap = A + (size_t)(m0 + lr) * lda + lc * 4;
    const float* Wp = W + (size_t)(n0 + lr) * ldw + lc * 4;

    for (int k0 = 0; k0 < K; k0 += 16) {
        float4 av = *(const float4*)(Ap + k0);
        float4 wv = *(const float4*)(Wp + k0);
        __syncthreads();
        As[(lc * 4 + 0) * 64 + lr] = av.x;
        As[(lc * 4 + 1) * 64 + lr] = av.y;
        As[(lc * 4 + 2) * 64 + lr] = av.z;
        As[(lc * 4 + 3) * 64 + lr] = av.w;
        Ws[(lc * 4 + 0) * 64 + lr] = wv.x;
        Ws[(lc * 4 + 1) * 64 + lr] = wv.y;
        Ws[(lc * 4 + 2) * 64 + lr] = wv.z;
        Ws[(lc * 4 + 3) * 64 + lr] = wv.w;
        __syncthreads();
#pragma unroll
        for (int k = 0; k < 16; ++k) {
            float4 a = *(const float4*)&As[k * 64 + ty * 4];
            float4 b = *(const float4*)&Ws[k * 64 + tx * 4];
            float aa[4] = {a.x, a.y, a.z, a.w};
            float bb[4] = {b.x, b.y, b.z, b.w};
#pragma unroll
            for (int i = 0; i < 4; ++i)
#pragma unroll
                for (int j = 0; j < 4; ++j) acc[i][j] += aa[i] * bb[j];
        }
    }

    const int jg = n0 + tx * 4;
    const int chunk = jg / n_per_chunk;
    const int jo = jg - chunk * n_per_chunk;
    float4 bv = make_float4(0.f, 0.f, 0.f, 0.f);
    if (bias) bv = *(const float4*)&bias[jg];
    float* Cb = C + (size_t)chunk * chunk_stride + jo;
#pragma unroll
    for (int i = 0; i < 4; ++i) {
        const int m = m0 + ty * 4 + i;
        float4 o;
        o.x = acc[i][0] + bv.x;
        o.y = acc[i][1] + bv.y;
        o.z = acc[i][2] + bv.z;
        o.w = acc[i][3] + bv.w;
        *(float4*)&Cb[(size_t)m * n_per_chunk] = o;
    }
}

// ---------------------------------------------------------------------------
// Persistent BiLSTM layer. 96 blocks x 256 threads (48 per direction, 16
// hidden units each), plain launch, trivially co-resident.
// BARRIER (round 6): the round-5 single-counter barrier serialized 96 atomic
// RMWs against 96 spin-readers on ONE LLC line (~21 us/step, VALUBusy 2.8%).
// Replaced with a contention-free stamp/flag barrier, zero RMW:
//   worker: store step to OWN padded line; spin-read broadcast flag.
//   master (wblk 0): wave 0 gathers all stamps in one vectorized load,
//                    __all-check, store flag.
// All cross-block traffic relaxed agent-scope (sc1 -> coherent LLC). Ordering:
// __syncthreads() drains vmcnt (h store LLC-acks) before stamps; flag seen =>
// stamps seen => h visible.
// ---------------------------------------------------------------------------
__global__ __launch_bounds__(LTHR, 1) void lstm_persist(
    const float* __restrict__ Whh,   // [2][3072][768]
    const float* __restrict__ G,     // [2][4][256][3072]
    float* __restrict__ hbuf,        // [2 parity][2 dir][768][4], zero-init
    float* __restrict__ Hout,        // [4][256][1536]
    unsigned int* __restrict__ stamps, // [2][LPB][SPAD], zero-init
    unsigned int* __restrict__ flags,  // [2][SPAD], zero-init
    int last)
{
    __shared__ __align__(16) float hsw[3104];  // swizzled h, float4 slot per k
    __shared__ float gl[64][4];
    __shared__ float cs[64];

    const int tid = threadIdx.x;
    const int dir = blockIdx.x / LPB;
    const int wblk = blockIdx.x - dir * LPB;
    const int u0 = wblk * UPB;

    const int ks = tid & 7;       // k-slice 0..7
    const int rg = tid >> 3;      // row-group 0..31 (2 rows each)
    const int jl0 = rg * 2, jl1 = jl0 + 1;           // 0..63
    const int j0 = (jl0 >> 4) * HD + u0 + (jl0 & 15);
    const int j1 = (jl1 >> 4) * HD + u0 + (jl1 & 15);

    // ---- preload weights into registers (2 rows x 24 float4) ----
    float4 w0r[24], w1r[24];
    {
        const float4* wp0 = (const float4*)(Whh + ((size_t)dir * G4 + j0) * HD);
        const float4* wp1 = (const float4*)(Whh + ((size_t)dir * G4 + j1) * HD);
#pragma unroll
        for (int it = 0; it < 24; ++it) {
            w0r[it] = wp0[it * 8 + ks];
            w1r[it] = wp1[it * 8 + ks];
        }
    }
    if (tid < 64) cs[tid] = 0.f;

    unsigned int* myflag = flags + dir * SPAD;
    unsigned int* mystamp = stamps + (size_t)(dir * LPB + wblk) * SPAD;
    const unsigned int* dirstamps = stamps + (size_t)dir * LPB * SPAD;
    const size_t bstr = (size_t)T1 * G4;
    const float4* hs4 = (const float4*)hsw;

    for (int s = 0; s < T1; ++s) {
        const int t = dir ? (T1 - 1 - s) : s;

        // prefetch ih-gate preactivations (independent of h)
        float gin0[4], gin1[4];
        if (ks == 0) {
            const size_t gb = ((size_t)dir * 4 * T1 + t) * G4;
#pragma unroll
            for (int b = 0; b < 4; ++b) {
                gin0[b] = G[gb + b * bstr + j0];
                gin1[b] = G[gb + b * bstr + j1];
            }
        }

        // ---- stage h into LDS (coalesced LLC read, XOR-swizzled write) ----
        const float* hsrc = hbuf + ((size_t)(s & 1) * 2 + dir) * (4 * HD);
#pragma unroll
        for (int i = 0; i < 12; ++i) {
            const int idx = tid + i * LTHR;      // 0..3071 = k*4 + b
            const float v = __hip_atomic_load(hsrc + idx,
                                              __ATOMIC_RELAXED, __HIP_MEMORY_SCOPE_AGENT);
            const int k = idx >> 2, b = idx & 3;
            const int ph = k ^ ((k >> 2) & 7);   // bijective XOR swizzle
            hsw[(ph << 2) + b] = v;
        }
        __syncthreads();

        // ---- gate GEMV: 2 rows x 96 k x 4 batch per thread ----
        float a00 = 0.f, a01 = 0.f, a02 = 0.f, a03 = 0.f;
        float a10 = 0.f, a11 = 0.f, a12 = 0.f, a13 = 0.f;
#pragma unroll
        for (int it = 0; it < 24; ++it) {
            const int kq = it * 8 + ks;
            const int sb = kq * 4;               // logical slot base
            const float4 w0 = w0r[it], w1 = w1r[it];
            const float4 hA = hs4[(sb + 0) ^ ks];
            const float4 hB = hs4[(sb + 1) ^ ks];
            const float4 hC = hs4[(sb + 2) ^ ks];
            const float4 hD = hs4[(sb + 3) ^ ks];
            a00 += w0.x * hA.x + w0.y * hB.x + w0.z * hC.x + w0.w * hD.x;
            a01 += w0.x * hA.y + w0.y * hB.y + w0.z * hC.y + w0.w * hD.y;
            a02 += w0.x * hA.z + w0.y * hB.z + w0.z * hC.z + w0.w * hD.z;
            a03 += w0.x * hA.w + w0.y * hB.w + w0.z * hC.w + w0.w * hD.w;
            a10 += w1.x * hA.x + w1.y * hB.x + w1.z * hC.x + w1.w * hD.x;
            a11 += w1.x * hA.y + w1.y * hB.y + w1.z * hC.y + w1.w * hD.y;
            a12 += w1.x * hA.z + w1.y * hB.z + w1.z * hC.z + w1.w * hD.z;
            a13 += w1.x * hA.w + w1.y * hB.w + w1.z * hC.w + w1.w * hD.w;
        }
#pragma unroll
        for (int off = 1; off < 8; off <<= 1) {
            a00 += __shfl_xor(a00, off); a01 += __shfl_xor(a01, off);
            a02 += __shfl_xor(a02, off); a03 += __shfl_xor(a03, off);
            a10 += __shfl_xor(a10, off); a11 += __shfl_xor(a11, off);
            a12 += __shfl_xor(a12, off); a13 += __shfl_xor(a13, off);
        }
        if (ks == 0) {
            gl[jl0][0] = a00 + gin0[0]; gl[jl0][1] = a01 + gin0[1];
            gl[jl0][2] = a02 + gin0[2]; gl[jl0][3] = a03 + gin0[3];
            gl[jl1][0] = a10 + gin1[0]; gl[jl1][1] = a11 + gin1[1];
            gl[jl1][2] = a12 + gin1[2]; gl[jl1][3] = a13 + gin1[3];
        }
        __syncthreads();

        // ---- cell update: 64 threads = 16 units x 4 batch ----
        if (tid < 64) {
            const int ui = tid >> 2, b = tid & 3;
            const int u = u0 + ui;
            const float gi = gl[0 * UPB + ui][b];
            const float gf = gl[1 * UPB + ui][b];
            const float gg = gl[2 * UPB + ui][b];
            const float go = gl[3 * UPB + ui][b];
            const float c = sigf(gf) * cs[tid] + sigf(gi) * tanhf(gg);
            const float h = sigf(go) * tanhf(c);
            cs[tid] = c;
            float* hdst = hbuf + ((size_t)((s + 1) & 1) * 2 + dir) * (4 * HD);
            __hip_atomic_store(hdst + (u << 2) + b, h,
                               __ATOMIC_RELAXED, __HIP_MEMORY_SCOPE_AGENT);
            Hout[((size_t)b * T1 + t) * (2 * HD) + dir * HD + u] = last ? tanhf(h) : h;
        }
        // drains vmcnt(0): h store LLC write-acks complete before stamps
        __syncthreads();

        // ---- stamp/flag barrier: no RMW, no shared-line writes ----
        const unsigned int target = (unsigned int)(s + 1);
        if (wblk == 0) {
            if (tid < 64) {  // master gather: one vectorized load per poll
                bool ok;
                do {
                    unsigned int v = target;
                    if (tid >= 1 && tid < LPB)
                        v = __hip_atomic_load(dirstamps + (size_t)tid * SPAD,
                                              __ATOMIC_RELAXED, __HIP_MEMORY_SCOPE_AGENT);
                    ok = __all(v >= target);
                    if (!ok) __builtin_amdgcn_s_sleep(1);
                } while (!ok);
                if (tid == 0)
                    __hip_atomic_store(myflag, target,
                                       __ATOMIC_RELAXED, __HIP_MEMORY_SCOPE_AGENT);
            }
        } else {
            if (tid == 0) {
                __hip_atomic_store(mystamp, target,
                                   __ATOMIC_RELAXED, __HIP_MEMORY_SCOPE_AGENT);
                while (__hip_atomic_load(myflag, __ATOMIC_RELAXED,
                                         __HIP_MEMORY_SCOPE_AGENT) < target) {
                    __builtin_amdgcn_s_sleep(1);
                }
            }
        }
        __syncthreads();
    }
}

// ---------------------------------------------------------------------------
// Attention: per (b,q) block.
// ---------------------------------------------------------------------------
__global__ __launch_bounds__(256) void attn_kernel(
    const float* __restrict__ hq,
    const float* __restrict__ hk,
    const float* __restrict__ w2p,
    const float* __restrict__ b2p,
    const float* __restrict__ am,
    const float* __restrict__ sm,
    const float* __restrict__ H3,
    float* __restrict__ sf)
{
    __shared__ float hql[HD];
    __shared__ float w2[HD];
    __shared__ float Ash[T1];
    __shared__ float red[1];
    const int tid = threadIdx.x;
    const int bq = blockIdx.x;
    const int b = bq >> 6;

    for (int e = tid; e < HD; e += 256) {
        hql[e] = hq[(size_t)bq * HD + e];
        w2[e] = w2p[e];
    }
    __syncthreads();

    const int lane = tid & 63, wid = tid >> 6;
    const float amv = am[bq];
    const float b2 = b2p[0];
    for (int k = wid; k < T1; k += 4) {
        const float* hkp = hk + ((size_t)b * T1 + k) * HD;
        float s = 0.f;
#pragma unroll
        for (int i = 0; i < 12; ++i) {
            const int e = i * 64 + lane;
            float v = hql[e] + hkp[e];
            v = v > 0.f ? v : 0.f;
            s += v * w2[e];
        }
#pragma unroll
        for (int off = 32; off; off >>= 1) s += __shfl_xor(s, off);
        if (lane == 0) {
            const float m = amv * sm[b * T1 + k];
            Ash[k] = (m == 0.f) ? 0.f : expf(s + b2);
        }
    }
    __syncthreads();

    if (tid < 64) {
        float p = Ash[tid] + Ash[tid + 64] + Ash[tid + 128] + Ash[tid + 192];
#pragma unroll
        for (int off = 32; off; off >>= 1) p += __shfl_xor(p, off);
        if (tid == 0) red[0] = fmaxf(p, 2e-15f);
    }
    __syncthreads();
    const float inv = 1.f / red[0];

    for (int d = tid; d < 2 * HD; d += 256) {
        const float* hp = H3 + (size_t)b * T1 * 2 * HD + d;
        float acc = 0.f;
        for (int k = 0; k < T1; ++k) acc += Ash[k] * hp[(size_t)k * 2 * HD];
        sf[(size_t)bq * 2 * HD + d] = acc * inv;
    }
}

__global__ __launch_bounds__(256) void val_kernel(
    const float* __restrict__ sf, const float* __restrict__ am,
    const float* __restrict__ vw, const float* __restrict__ vb,
    float* __restrict__ val)
{
    __shared__ float red[4];
    const int b = blockIdx.x, tid = threadIdx.x;
    float num = 0.f;
    for (int q = 0; q < NS2; ++q) num += am[b * NS2 + q];
    float acc = 0.f;
    for (int d = tid; d < 2 * HD; d += 256) {
        float s = 0.f;
        for (int q = 0; q < NS2; ++q) s += sf[((size_t)(b * NS2 + q)) * 2 * HD + d];
        acc += (s / num) * vw[d];
    }
#pragma unroll
    for (int off = 32; off; off >>= 1) acc += __shfl_xor(acc, off);
    if ((tid & 63) == 0) red[tid >> 6] = acc;
    __syncthreads();
    if (tid == 0) val[b] = red[0] + red[1] + red[2] + red[3] + vb[0];
}

__global__ __launch_bounds__(256) void final_kernel(
    const float* __restrict__ Tb,   // [3][256][768]
    const float* __restrict__ act,  // [4][64][768]
    const float* __restrict__ bias, // [3]
    const float* __restrict__ val,  // [4]
    float* __restrict__ out)        // [256][3]
{
    __shared__ float adv[192];
    __shared__ float red[4];
    const int b = blockIdx.x, tid = threadIdx.x;
    const int lane = tid & 63, wid = tid >> 6;

    for (int idx = wid; idx < 192; idx += 4) {
        const int q = idx / 3, l = idx - q * 3;
        const float* tp = Tb + (size_t)l * T1 * HD + (size_t)(b * NS2 + q) * HD;
        const float* ap = act + (size_t)(b * NS2 + q) * HD;
        float s = 0.f;
#pragma unroll
        for (int i = 0; i < 12; ++i) {
            const int h = i * 64 + lane;
            s += tp[h] * ap[h];
        }
#pragma unroll
        for (int off = 32; off; off >>= 1) s += __shfl_xor(s, off);
        if (lane == 0) adv[idx] = s + bias[l];
    }
    __syncthreads();
    float part = (tid < 192) ? adv[tid] : 0.f;
#pragma unroll
    for (int off = 32; off; off >>= 1) part += __shfl_xor(part, off);
    if (lane == 0) red[wid] = part;
    __syncthreads();
    const float mean = (red[0] + red[1] + red[2] + red[3]) * (1.f / 192.f);
    const float vv = val[b];
    for (int idx = tid; idx < 192; idx += 256) {
        const int q = idx / 3, l = idx - q * 3;
        out[(size_t)(b * NS2 + q) * NL + l] = vv + adv[idx] - mean;
    }
}

// ---------------------------------------------------------------------------
extern "C" void kernel_launch(void* const* d_in, const int* in_sizes, int n_in,
                              void* d_out, int out_size, void* d_ws, size_t ws_size,
                              hipStream_t stream)
{
    const float* states = (const float*)d_in[0];
    const float* state_mask = (const float*)d_in[1];
    const float* actions = (const float*)d_in[2];
    const float* actions_mask = (const float*)d_in[3];
    const float* Wih0 = (const float*)d_in[4];
    const float* Whh0 = (const float*)d_in[5];
    const float* b0 = (const float*)d_in[6];
    const float* Wih12 = (const float*)d_in[7];
    const float* Whh12 = (const float*)d_in[8];
    const float* b12 = (const float*)d_in[9];
    const float* aW1 = (const float*)d_in[10];
    const float* ab1 = (const float*)d_in[11];
    const float* aW2 = (const float*)d_in[12];
    const float* ab2 = (const float*)d_in[13];
    const float* vW = (const float*)d_in[14];
    const float* vb = (const float*)d_in[15];
    const float* wgt = (const float*)d_in[16];
    const float* bias = (const float*)d_in[17];
    float* out = (float*)d_out;

    float* ws = (float*)d_ws;
    float* G = ws;                        // 6291456 floats
    float* B1 = G + 6291456;              // 1572864
    float* B2 = B1 + 1572864;             // 1572864
    float* hbuf = B2 + 1572864;           // 12288 floats
    unsigned int* stamps = (unsigned int*)(hbuf + 12288);   // 2*LPB*SPAD
    unsigned int* flags = stamps + 2 * LPB * SPAD;          // 2*SPAD
    const size_t syncBytes = (12288 + 2 * LPB * SPAD + 2 * SPAD) * 4;
    // attention-phase aliases over G:
    float* hq = G;                        // 196608
    float* hkb = G + 196608;              // 786432
    float* sf = G + 983040;               // 393216
    float* Tb = G + 1376256;              // 589824
    float* val = G + 1966080;             // 4

    const dim3 blk(256);
    const long long gstride = (long long)4 * T1 * G4;

    const float* WhhL[3] = {Whh0, Whh12, Whh12 + (size_t)2 * G4 * HD};
    float* HoutL[3] = {B1, B2, B1};

    for (int l = 0; l < 3; ++l) {
        hipMemsetAsync(hbuf, 0, syncBytes, stream);  // h ping-pong + stamps + flags
        if (l == 0) {
            gemm_f32<<<dim3(6144 / 64, 1024 / 64), blk, 0, stream>>>(
                states, HD, Wih0, HD, b0, G, HD, G4, gstride);
        } else {
            const float* src = (l == 1) ? B1 : B2;
            const float* Wih = Wih12 + (size_t)(l - 1) * 6144 * 1536;
            const float* bb = b12 + (size_t)(l - 1) * 6144;
            gemm_f32<<<dim3(6144 / 64, 1024 / 64), blk, 0, stream>>>(
                src, 2 * HD, Wih, 2 * HD, bb, G, 2 * HD, G4, gstride);
        }
        lstm_persist<<<dim3(LBLK), dim3(LTHR), 0, stream>>>(
            WhhL[l], G, hbuf, HoutL[l], stamps, flags, (l == 2) ? 1 : 0);
    }

    // ---------------- attention ----------------
    gemm_f32<<<dim3(768 / 64, 256 / 64), blk, 0, stream>>>(
        actions, HD, aW1, 2304, ab1, hq, HD, HD, 0);
    gemm_f32<<<dim3(768 / 64, 1024 / 64), blk, 0, stream>>>(
        B1, 2 * HD, aW1 + 768, 2304, nullptr, hkb, 2 * HD, HD, 0);
    attn_kernel<<<dim3(256), blk, 0, stream>>>(hq, hkb, aW2, ab2, actions_mask,
                                               state_mask, B1, sf);
    val_kernel<<<dim3(4), blk, 0, stream>>>(sf, actions_mask, vW, vb, val);
    for (int l = 0; l < NL; ++l) {
        gemm_f32<<<dim3(768 / 64, 256 / 64), blk, 0, stream>>>(
            sf, 2 * HD, wgt + (size_t)l * HD * 2 * HD, 2 * HD, nullptr,
            Tb + (size_t)l * T1 * HD, 2 * HD, HD, 0);
    }
    final_kernel<<<dim3(4), blk, 0, stream>>>(Tb, actions, bias, val, out);
}